// Round 24
// baseline (51.058 us; speedup 1.0000x reference)
//
#include <hip/hip_runtime.h>

// LocalL1Loss: out = mean_{n,h,w} min_{7x7 shift} mean_c |in - shifted(tgt, zero-pad)|
// inputs/targets: (16, 3, 512, 512) fp32. Output: scalar fp32.
// R23: R22 (46.4us) with 3-bit XOR key 4*(r&7), stride 92. R22's residual 6M
// conflicts = staging writes (per-row class-triple at offsets {0,32,64} piled
// on one bank-quad; 2-bit key + base 16r couldn't spread it). 3-bit key makes
// 8 consecutive rows' triples hit 8 distinct quads. Eval reads stay uniform
// at 16-lane granularity (key bit 2 alternates even/odd quad sets per row).

constexpr int N = 16, C = 3, H = 512, W = 512;
constexpr int K = 7, HALO = 3;
constexpr int TH = 64, TW = 64;            // output tile per block
constexpr int SM_ROWS = 70;                // 64 + 2*3
constexpr int SM_STRIDE = 92;              // row stride; XOR positions <= 88
constexpr int BLK = 512;                   // 64 rows x 8 strips of 8 = 8 waves
constexpr int NP4 = C * SM_ROWS * 18;      // 3780 float4 staging positions

__global__ __launch_bounds__(BLK, 4)
void local_l1_kernel(const float* __restrict__ inputs,
                     const float* __restrict__ targets,
                     float* __restrict__ out) {
    __shared__ float sm_f[C * SM_ROWS * SM_STRIDE];   // 77,280 B -> 2 blocks/CU

    const int tid = threadIdx.x;
    const int w0 = blockIdx.x * TW;
    const int h0 = blockIdx.y * TH;
    const int n  = blockIdx.z;

    const int tx = tid & 7;     // strip index (w)
    const int ty = tid >> 3;    // row in tile (0..63)

    // ---- issue input loads FIRST so they overlap the staging burst ----
    const float* ibase = inputs + ((size_t)n * C * H + (size_t)(h0 + ty)) * W
                       + (w0 + tx * 8);
    float4 ia[3], ib[3];
    #pragma unroll
    for (int c = 0; c < 3; ++c) {
        ia[c] = *reinterpret_cast<const float4*>(ibase + (size_t)c * H * W);
        ib[c] = *reinterpret_cast<const float4*>(ibase + (size_t)c * H * W + 4);
    }

    // ---- stage targets tile into LDS as fp32, row-XOR swizzled (3-bit key) --
    // position p = c*(70*18) + r*18 + d4 ; LDS idx (c*70+r)*92 + (4d4 ^ 4(r&7))
    // global: row h0-3+r, col w0-4+4*d4. Step 512 = 28*18 + 8.
    const float* tbase = targets + (size_t)n * C * H * W;
    const bool interior = (h0 != 0) && (h0 != H - TH) && (w0 != 0) && (w0 != W - TW);
    {
        int r  = tid / 18;
        int d4 = tid - r * 18;
        int c  = 0;
        if (interior) {
            float4 v[4]; int idx[4];
            #pragma unroll
            for (int b = 0; b < 4; ++b) {              // iters 0..3
                v[b] = *reinterpret_cast<const float4*>(
                    tbase + ((size_t)c * H + (h0 - HALO + r)) * W + (w0 - 4 + 4 * d4));
                idx[b] = (c * SM_ROWS + r) * SM_STRIDE + ((4 * d4) ^ (4 * (r & 7)));
                r += 28; d4 += 8;
                if (d4 >= 18) { d4 -= 18; r += 1; }
                if (r >= SM_ROWS) { r -= SM_ROWS; c += 1; }
            }
            #pragma unroll
            for (int b = 0; b < 4; ++b)
                *reinterpret_cast<float4*>(&sm_f[idx[b]]) = v[b];
            #pragma unroll
            for (int b = 0; b < 3; ++b) {              // iters 4..6
                v[b] = *reinterpret_cast<const float4*>(
                    tbase + ((size_t)c * H + (h0 - HALO + r)) * W + (w0 - 4 + 4 * d4));
                idx[b] = (c * SM_ROWS + r) * SM_STRIDE + ((4 * d4) ^ (4 * (r & 7)));
                r += 28; d4 += 8;
                if (d4 >= 18) { d4 -= 18; r += 1; }
                if (r >= SM_ROWS) { r -= SM_ROWS; c += 1; }
            }
            #pragma unroll
            for (int b = 0; b < 3; ++b)
                *reinterpret_cast<float4*>(&sm_f[idx[b]]) = v[b];
            if (tid < NP4 - 7 * BLK) {                 // tail: 196 threads
                float4 vv = *reinterpret_cast<const float4*>(
                    tbase + ((size_t)c * H + (h0 - HALO + r)) * W + (w0 - 4 + 4 * d4));
                *reinterpret_cast<float4*>(
                    &sm_f[(c * SM_ROWS + r) * SM_STRIDE + ((4 * d4) ^ (4 * (r & 7)))]) = vv;
            }
        } else {
            #pragma unroll
            for (int it = 0; it < 8; ++it) {
                if (it < 7 || tid < NP4 - 7 * BLK) {
                    const int gr = h0 - HALO + r;
                    const int gc = w0 - 4 + 4 * d4;
                    const bool ok = ((unsigned)gr < (unsigned)H) && (gc >= 0) && (gc + 4 <= W);
                    const int grc = gr < 0 ? 0 : (gr > H - 1 ? H - 1 : gr);
                    const int gcc = gc < 0 ? 0 : (gc > W - 4 ? W - 4 : gc);
                    float4 vv = *reinterpret_cast<const float4*>(
                        tbase + ((size_t)c * H + grc) * W + gcc);
                    if (!ok) { vv.x = 0.f; vv.y = 0.f; vv.z = 0.f; vv.w = 0.f; }
                    *reinterpret_cast<float4*>(
                        &sm_f[(c * SM_ROWS + r) * SM_STRIDE + ((4 * d4) ^ (4 * (r & 7)))]) = vv;
                }
                r += 28; d4 += 8;
                if (d4 >= 18) { d4 -= 18; r += 1; }
                if (r >= SM_ROWS) { r -= SM_ROWS; c += 1; }
            }
        }
    }

    float in[3][8];
    #pragma unroll
    for (int c = 0; c < 3; ++c) {
        in[c][0] = ia[c].x; in[c][1] = ia[c].y; in[c][2] = ia[c].z; in[c][3] = ia[c].w;
        in[c][4] = ib[c].x; in[c][5] = ib[c].y; in[c][6] = ib[c].z; in[c][7] = ib[c].w;
    }
    __syncthreads();

    // ---- main loop: 8 outputs/thread, fp32, min3-folded shifts ----
    float best[8];
    #pragma unroll
    for (int o = 0; o < 8; ++o) best[o] = 3.0e38f;

    #pragma unroll
    for (int di = 0; di < K; ++di) {
        const int row = ty + di;
        const int xr = 4 * (row & 7);
        // 16 floats per channel: LDS cols 8tx..8tx+15 (global w0-4+8tx ..)
        float fr[3][16];
        #pragma unroll
        for (int c = 0; c < 3; ++c) {
            const float* rowp = &sm_f[(c * SM_ROWS + row) * SM_STRIDE];
            float4 v0 = *reinterpret_cast<const float4*>(rowp + ((8 * tx) ^ xr));
            float4 v1 = *reinterpret_cast<const float4*>(rowp + ((8 * tx + 4) ^ xr));
            float4 v2 = *reinterpret_cast<const float4*>(rowp + ((8 * tx + 8) ^ xr));
            float4 v3 = *reinterpret_cast<const float4*>(rowp + ((8 * tx + 12) ^ xr));
            fr[c][0]  = v0.x; fr[c][1]  = v0.y; fr[c][2]  = v0.z; fr[c][3]  = v0.w;
            fr[c][4]  = v1.x; fr[c][5]  = v1.y; fr[c][6]  = v1.z; fr[c][7]  = v1.w;
            fr[c][8]  = v2.x; fr[c][9]  = v2.y; fr[c][10] = v2.z; fr[c][11] = v2.w;
            fr[c][12] = v3.x; fr[c][13] = v3.y; fr[c][14] = v3.z; fr[c][15] = v3.w;
        }
        // output o, shift dj: target fr[o + dj + 1]
        #pragma unroll
        for (int o = 0; o < 8; ++o) {
            float d0 = fabsf(in[0][o] - fr[0][o + 1])
                     + fabsf(in[1][o] - fr[1][o + 1])
                     + fabsf(in[2][o] - fr[2][o + 1]);
            float d1 = fabsf(in[0][o] - fr[0][o + 2])
                     + fabsf(in[1][o] - fr[1][o + 2])
                     + fabsf(in[2][o] - fr[2][o + 2]);
            best[o] = fminf(fminf(best[o], d0), d1);
            float d2 = fabsf(in[0][o] - fr[0][o + 3])
                     + fabsf(in[1][o] - fr[1][o + 3])
                     + fabsf(in[2][o] - fr[2][o + 3]);
            float d3 = fabsf(in[0][o] - fr[0][o + 4])
                     + fabsf(in[1][o] - fr[1][o + 4])
                     + fabsf(in[2][o] - fr[2][o + 4]);
            best[o] = fminf(fminf(best[o], d2), d3);
            float d4 = fabsf(in[0][o] - fr[0][o + 5])
                     + fabsf(in[1][o] - fr[1][o + 5])
                     + fabsf(in[2][o] - fr[2][o + 5]);
            float d5 = fabsf(in[0][o] - fr[0][o + 6])
                     + fabsf(in[1][o] - fr[1][o + 6])
                     + fabsf(in[2][o] - fr[2][o + 6]);
            best[o] = fminf(fminf(best[o], d4), d5);
            float d6 = fabsf(in[0][o] - fr[0][o + 7])
                     + fabsf(in[1][o] - fr[1][o + 7])
                     + fabsf(in[2][o] - fr[2][o + 7]);
            best[o] = fminf(best[o], d6);
        }
    }

    float part = 0.0f;
    #pragma unroll
    for (int o = 0; o < 8; ++o) part += best[o];

    // wave (64-lane) reduction, then cross-wave via LDS
    #pragma unroll
    for (int off = 32; off > 0; off >>= 1)
        part += __shfl_down(part, off, 64);

    __shared__ float wsum[BLK / 64];
    if ((tid & 63) == 0) wsum[tid >> 6] = part;
    __syncthreads();
    if (tid == 0) {
        float total = 0.0f;
        #pragma unroll
        for (int i = 0; i < BLK / 64; ++i) total += wsum[i];
        atomicAdd(out, total * (1.0f / (3.0f * (float)N * (float)H * (float)W)));
    }
}

extern "C" void kernel_launch(void* const* d_in, const int* in_sizes, int n_in,
                              void* d_out, int out_size, void* d_ws, size_t ws_size,
                              hipStream_t stream) {
    const float* inputs  = (const float*)d_in[0];
    const float* targets = (const float*)d_in[1];
    float* out = (float*)d_out;

    (void)hipMemsetAsync(out, 0, sizeof(float), stream);
    dim3 grid(W / TW, H / TH, N);
    local_l1_kernel<<<grid, BLK, 0, stream>>>(inputs, targets, out);
}

// Round 25
// 46.373 us; speedup vs baseline: 1.1010x; 1.1010x over previous
//
#include <hip/hip_runtime.h>

// LocalL1Loss: out = mean_{n,h,w} min_{7x7 shift} mean_c |in - shifted(tgt, zero-pad)|
// inputs/targets: (16, 3, 512, 512) fp32. Output: scalar fp32.
// R24: REVERT to R22 (best, 46.4us). R23's 3-bit key + stride 92 broke
// eval-read uniformity (conflicts 6.0M -> 12.2M, +4.6us). R22's 2-bit
// row-XOR key with stride 80 is load-bearing for BOTH read and write phases.
// col c of row r stored at c ^ (4*(r&3)), stride 80.

constexpr int N = 16, C = 3, H = 512, W = 512;
constexpr int K = 7, HALO = 3;
constexpr int TH = 64, TW = 64;            // output tile per block
constexpr int SM_ROWS = 70;                // 64 + 2*3
constexpr int SM_STRIDE = 80;              // row stride; XOR positions <= 75
constexpr int BLK = 512;                   // 64 rows x 8 strips of 8 = 8 waves
constexpr int NP4 = C * SM_ROWS * 18;      // 3780 float4 staging positions

__global__ __launch_bounds__(BLK, 4)
void local_l1_kernel(const float* __restrict__ inputs,
                     const float* __restrict__ targets,
                     float* __restrict__ out) {
    __shared__ float sm_f[C * SM_ROWS * SM_STRIDE];   // 67,200 B -> 2 blocks/CU

    const int tid = threadIdx.x;
    const int w0 = blockIdx.x * TW;
    const int h0 = blockIdx.y * TH;
    const int n  = blockIdx.z;

    const int tx = tid & 7;     // strip index (w)
    const int ty = tid >> 3;    // row in tile (0..63)

    // ---- issue input loads FIRST so they overlap the staging burst ----
    const float* ibase = inputs + ((size_t)n * C * H + (size_t)(h0 + ty)) * W
                       + (w0 + tx * 8);
    float4 ia[3], ib[3];
    #pragma unroll
    for (int c = 0; c < 3; ++c) {
        ia[c] = *reinterpret_cast<const float4*>(ibase + (size_t)c * H * W);
        ib[c] = *reinterpret_cast<const float4*>(ibase + (size_t)c * H * W + 4);
    }

    // ---- stage targets tile into LDS as fp32, row-XOR swizzled ----
    // position p = c*(70*18) + r*18 + d4 ; LDS idx (c*70+r)*80 + (4d4 ^ 4(r&3))
    // global: row h0-3+r, col w0-4+4*d4. Step 512 = 28*18 + 8.
    const float* tbase = targets + (size_t)n * C * H * W;
    const bool interior = (h0 != 0) && (h0 != H - TH) && (w0 != 0) && (w0 != W - TW);
    {
        int r  = tid / 18;
        int d4 = tid - r * 18;
        int c  = 0;
        if (interior) {
            float4 v[4]; int idx[4];
            #pragma unroll
            for (int b = 0; b < 4; ++b) {              // iters 0..3
                v[b] = *reinterpret_cast<const float4*>(
                    tbase + ((size_t)c * H + (h0 - HALO + r)) * W + (w0 - 4 + 4 * d4));
                idx[b] = (c * SM_ROWS + r) * SM_STRIDE + ((4 * d4) ^ (4 * (r & 3)));
                r += 28; d4 += 8;
                if (d4 >= 18) { d4 -= 18; r += 1; }
                if (r >= SM_ROWS) { r -= SM_ROWS; c += 1; }
            }
            #pragma unroll
            for (int b = 0; b < 4; ++b)
                *reinterpret_cast<float4*>(&sm_f[idx[b]]) = v[b];
            #pragma unroll
            for (int b = 0; b < 3; ++b) {              // iters 4..6
                v[b] = *reinterpret_cast<const float4*>(
                    tbase + ((size_t)c * H + (h0 - HALO + r)) * W + (w0 - 4 + 4 * d4));
                idx[b] = (c * SM_ROWS + r) * SM_STRIDE + ((4 * d4) ^ (4 * (r & 3)));
                r += 28; d4 += 8;
                if (d4 >= 18) { d4 -= 18; r += 1; }
                if (r >= SM_ROWS) { r -= SM_ROWS; c += 1; }
            }
            #pragma unroll
            for (int b = 0; b < 3; ++b)
                *reinterpret_cast<float4*>(&sm_f[idx[b]]) = v[b];
            if (tid < NP4 - 7 * BLK) {                 // tail: 196 threads
                float4 vv = *reinterpret_cast<const float4*>(
                    tbase + ((size_t)c * H + (h0 - HALO + r)) * W + (w0 - 4 + 4 * d4));
                *reinterpret_cast<float4*>(
                    &sm_f[(c * SM_ROWS + r) * SM_STRIDE + ((4 * d4) ^ (4 * (r & 3)))]) = vv;
            }
        } else {
            #pragma unroll
            for (int it = 0; it < 8; ++it) {
                if (it < 7 || tid < NP4 - 7 * BLK) {
                    const int gr = h0 - HALO + r;
                    const int gc = w0 - 4 + 4 * d4;
                    const bool ok = ((unsigned)gr < (unsigned)H) && (gc >= 0) && (gc + 4 <= W);
                    const int grc = gr < 0 ? 0 : (gr > H - 1 ? H - 1 : gr);
                    const int gcc = gc < 0 ? 0 : (gc > W - 4 ? W - 4 : gc);
                    float4 vv = *reinterpret_cast<const float4*>(
                        tbase + ((size_t)c * H + grc) * W + gcc);
                    if (!ok) { vv.x = 0.f; vv.y = 0.f; vv.z = 0.f; vv.w = 0.f; }
                    *reinterpret_cast<float4*>(
                        &sm_f[(c * SM_ROWS + r) * SM_STRIDE + ((4 * d4) ^ (4 * (r & 3)))]) = vv;
                }
                r += 28; d4 += 8;
                if (d4 >= 18) { d4 -= 18; r += 1; }
                if (r >= SM_ROWS) { r -= SM_ROWS; c += 1; }
            }
        }
    }

    float in[3][8];
    #pragma unroll
    for (int c = 0; c < 3; ++c) {
        in[c][0] = ia[c].x; in[c][1] = ia[c].y; in[c][2] = ia[c].z; in[c][3] = ia[c].w;
        in[c][4] = ib[c].x; in[c][5] = ib[c].y; in[c][6] = ib[c].z; in[c][7] = ib[c].w;
    }
    __syncthreads();

    // ---- main loop: 8 outputs/thread, fp32, min3-folded shifts ----
    float best[8];
    #pragma unroll
    for (int o = 0; o < 8; ++o) best[o] = 3.0e38f;

    #pragma unroll
    for (int di = 0; di < K; ++di) {
        const int row = ty + di;
        const int xr = 4 * (row & 3);
        // 16 floats per channel: LDS cols 8tx..8tx+15 (global w0-4+8tx ..)
        float fr[3][16];
        #pragma unroll
        for (int c = 0; c < 3; ++c) {
            const float* rowp = &sm_f[(c * SM_ROWS + row) * SM_STRIDE];
            float4 v0 = *reinterpret_cast<const float4*>(rowp + ((8 * tx) ^ xr));
            float4 v1 = *reinterpret_cast<const float4*>(rowp + ((8 * tx + 4) ^ xr));
            float4 v2 = *reinterpret_cast<const float4*>(rowp + ((8 * tx + 8) ^ xr));
            float4 v3 = *reinterpret_cast<const float4*>(rowp + ((8 * tx + 12) ^ xr));
            fr[c][0]  = v0.x; fr[c][1]  = v0.y; fr[c][2]  = v0.z; fr[c][3]  = v0.w;
            fr[c][4]  = v1.x; fr[c][5]  = v1.y; fr[c][6]  = v1.z; fr[c][7]  = v1.w;
            fr[c][8]  = v2.x; fr[c][9]  = v2.y; fr[c][10] = v2.z; fr[c][11] = v2.w;
            fr[c][12] = v3.x; fr[c][13] = v3.y; fr[c][14] = v3.z; fr[c][15] = v3.w;
        }
        // output o, shift dj: target fr[o + dj + 1]
        #pragma unroll
        for (int o = 0; o < 8; ++o) {
            float d0 = fabsf(in[0][o] - fr[0][o + 1])
                     + fabsf(in[1][o] - fr[1][o + 1])
                     + fabsf(in[2][o] - fr[2][o + 1]);
            float d1 = fabsf(in[0][o] - fr[0][o + 2])
                     + fabsf(in[1][o] - fr[1][o + 2])
                     + fabsf(in[2][o] - fr[2][o + 2]);
            best[o] = fminf(fminf(best[o], d0), d1);
            float d2 = fabsf(in[0][o] - fr[0][o + 3])
                     + fabsf(in[1][o] - fr[1][o + 3])
                     + fabsf(in[2][o] - fr[2][o + 3]);
            float d3 = fabsf(in[0][o] - fr[0][o + 4])
                     + fabsf(in[1][o] - fr[1][o + 4])
                     + fabsf(in[2][o] - fr[2][o + 4]);
            best[o] = fminf(fminf(best[o], d2), d3);
            float d4 = fabsf(in[0][o] - fr[0][o + 5])
                     + fabsf(in[1][o] - fr[1][o + 5])
                     + fabsf(in[2][o] - fr[2][o + 5]);
            float d5 = fabsf(in[0][o] - fr[0][o + 6])
                     + fabsf(in[1][o] - fr[1][o + 6])
                     + fabsf(in[2][o] - fr[2][o + 6]);
            best[o] = fminf(fminf(best[o], d4), d5);
            float d6 = fabsf(in[0][o] - fr[0][o + 7])
                     + fabsf(in[1][o] - fr[1][o + 7])
                     + fabsf(in[2][o] - fr[2][o + 7]);
            best[o] = fminf(best[o], d6);
        }
    }

    float part = 0.0f;
    #pragma unroll
    for (int o = 0; o < 8; ++o) part += best[o];

    // wave (64-lane) reduction, then cross-wave via LDS
    #pragma unroll
    for (int off = 32; off > 0; off >>= 1)
        part += __shfl_down(part, off, 64);

    __shared__ float wsum[BLK / 64];
    if ((tid & 63) == 0) wsum[tid >> 6] = part;
    __syncthreads();
    if (tid == 0) {
        float total = 0.0f;
        #pragma unroll
        for (int i = 0; i < BLK / 64; ++i) total += wsum[i];
        atomicAdd(out, total * (1.0f / (3.0f * (float)N * (float)H * (float)W)));
    }
}

extern "C" void kernel_launch(void* const* d_in, const int* in_sizes, int n_in,
                              void* d_out, int out_size, void* d_ws, size_t ws_size,
                              hipStream_t stream) {
    const float* inputs  = (const float*)d_in[0];
    const float* targets = (const float*)d_in[1];
    float* out = (float*)d_out;

    (void)hipMemsetAsync(out, 0, sizeof(float), stream);
    dim3 grid(W / TW, H / TH, N);
    local_l1_kernel<<<grid, BLK, 0, stream>>>(inputs, targets, out);
}